// Round 19
// baseline (5950.255 us; speedup 1.0000x reference)
//
#include <hip/hip_runtime.h>
#include <math.h>

// PhaseRefinement fused kernel, v19 = v15 (best, 380us) + pipe-overlap fixes.
// R18 arithmetic: R15's group cost = SUM of pipe times (10.9k cyc measured
// vs LDS 4.6k + L1 2.0k + VALU 4.4k), not MAX -- barrier-locked waves move
// in lockstep [LDS burst][VALU burst], pipes never overlap. v15's
// '#pragma unroll 1' (anti-spill relic of R7) also FORBADE the compiler
// from interleaving chunk-b ds_reads under chunk-a FMAs. Changes:
//  1. fully unroll the 2-chunk group body -> cross-chunk ILP, compiler
//     interleaves reads/FMAs with fine-grained lgkmcnt (its strength, m97);
//  2. s_setprio(1) around the FMA cluster (T5: pays when waves have role
//     diversity, which the interleave creates);
//  3. stats from a dedicated uniform ds_read (runtime-wv LDS *address* is
//     fine; rule20 is about register arrays) -> no branch in FMA cluster;
//  4. phase-B stores non-temporal (write-only; protects x L2 residency).
// MFMA-bf16 ruled out analytically: alpha=c*rsqrt(c^2 var+1e-5) has slope
// ~316 near c~0 (~1% of rows) -> bf16 dot error ~0.01 -> absmax ~3. Dots
// must stay f32 VALU.
//
// out = x + LN(c*x)*gamma + beta; LN(c*x) collapses to
//   normed = gamma*(alpha*x - alpha*mu) + beta,
//   alpha = c*rsqrt(c^2*var + 1e-5), mu/var = plain row stats of x.

constexpr int Dh     = 4096;
constexpr int Ph     = 16;
constexpr int NPL    = 32;
constexpr int CHUNK  = 256;           // 64 lanes * 4 floats
constexpr int GCH    = 2;             // chunks per group (512 cols)
constexpr int NGRP   = Dh / (CHUNK * GCH);   // 8
constexpr int RPB    = 8;             // rows per block
constexpr int NW     = 8;             // waves per block
constexpr int PPW    = NPL / NW;      // 4 planes per wave
constexpr int BLOCK  = 64 * NW;       // 512

typedef float float4n __attribute__((ext_vector_type(4)));

__device__ __forceinline__ void stage_chunk(const float* src, float* ldsdst) {
    __builtin_amdgcn_global_load_lds(
        (const __attribute__((address_space(1))) void*)src,
        (__attribute__((address_space(3))) void*)ldsdst, 16, 0, 0);
}

__global__ __launch_bounds__(BLOCK, 4)
void phase_fused(const float* __restrict__ x,
                 const float* __restrict__ Wr,
                 const float* __restrict__ br,
                 const float* __restrict__ Wo,
                 const float* __restrict__ bo,
                 const float* __restrict__ gamma,
                 const float* __restrict__ beta,
                 float* __restrict__ out)
{
    __shared__ float x_lds[2][GCH][RPB][CHUNK];   // 32 KB double buffer
    __shared__ float dots_lds[RPB][NPL];
    __shared__ float stats_lds[RPB][2];
    __shared__ float scale_lds[RPB][2];

    const int t    = threadIdx.x;
    const int wv   = t >> 6;
    const int lane = t & 63;
    const size_t rowbase = (size_t)blockIdx.x * RPB;

    // Per-wave W pointers (lane offset folded in).
    const float* wrow[PPW];
#pragma unroll
    for (int p = 0; p < PPW; ++p) {
        const int q = wv * PPW + p;
        wrow[p] = ((q < Ph) ? (Wr + (size_t)q * Dh) : (Wo + (size_t)(q - Ph) * Dh))
                  + lane * 4;
    }
    // Wave wv stages row wv; global src per-lane, LDS dst wave-uniform linear.
    const float* xsrc = x + (rowbase + wv) * (size_t)Dh + lane * 4;
    // Uniform stats read address (runtime wv in LDS address is fine).
    const float* xstat_base = &x_lds[0][0][wv][lane * 4];

    float acc[RPB][PPW];
#pragma unroll
    for (int r = 0; r < RPB; ++r)
#pragma unroll
        for (int p = 0; p < PPW; ++p) acc[r][p] = 0.f;
    float sx = 0.f, sxx = 0.f;

    // Stage one 512-col group (2 chunks) of this wave's row into buf.
    auto stage_group = [&](int g, int buf) {
#pragma unroll
        for (int k = 0; k < GCH; ++k)
            stage_chunk(xsrc + (size_t)(g * GCH + k) * CHUNK,
                        &x_lds[buf][k][wv][0]);
    };

    // Compute one group from buf. FULLY unrolled (both chunks visible to
    // the scheduler -> chunk-b reads interleave under chunk-a FMAs).
    auto compute_group = [&](int g, int buf) {
#pragma unroll
        for (int k = 0; k < GCH; ++k) {
            const int off = (g * GCH + k) * CHUNK;
            float4 w4[PPW];
#pragma unroll
            for (int p = 0; p < PPW; ++p)
                w4[p] = *(const float4*)(wrow[p] + off);
            float4 x4[RPB];
#pragma unroll
            for (int r = 0; r < RPB; ++r)
                x4[r] = *(const float4*)(&x_lds[buf][k][r][lane * 4]);
            // Stats: dedicated uniform ds_read of row wv (no branch below).
            float4 xs = *(const float4*)(&x_lds[buf][k][wv][lane * 4]);
            sx  += xs.x + xs.y + xs.z + xs.w;
            sxx += xs.x*xs.x + xs.y*xs.y + xs.z*xs.z + xs.w*xs.w;

            __builtin_amdgcn_s_setprio(1);
#pragma unroll
            for (int r = 0; r < RPB; ++r)
#pragma unroll
                for (int p = 0; p < PPW; ++p)
                    acc[r][p] += x4[r].x*w4[p].x + x4[r].y*w4[p].y
                               + x4[r].z*w4[p].z + x4[r].w*w4[p].w;
            __builtin_amdgcn_s_setprio(0);
        }
    };

    // Software pipeline, 9 barriers (proven). stage(g+1) issued before
    // compute(g); the barrier's vmcnt(0) drain is covered by group compute.
    stage_group(0, 0);
    __syncthreads();
    stage_group(1, 1); compute_group(0, 0);
    __syncthreads();
    stage_group(2, 0); compute_group(1, 1);
    __syncthreads();
    stage_group(3, 1); compute_group(2, 0);
    __syncthreads();
    stage_group(4, 0); compute_group(3, 1);
    __syncthreads();
    stage_group(5, 1); compute_group(4, 0);
    __syncthreads();
    stage_group(6, 0); compute_group(5, 1);
    __syncthreads();
    stage_group(7, 1); compute_group(6, 0);
    __syncthreads();
    compute_group(7, 1);

    // Butterfly-reduce accumulators across the 64 lanes.
#pragma unroll
    for (int r = 0; r < RPB; ++r)
#pragma unroll
        for (int p = 0; p < PPW; ++p) {
            float v = acc[r][p];
#pragma unroll
            for (int m = 1; m < 64; m <<= 1) v += __shfl_xor(v, m, 64);
            if (lane == 0) dots_lds[r][wv * PPW + p] = v;
        }
#pragma unroll
    for (int m = 1; m < 64; m <<= 1) {
        sx  += __shfl_xor(sx, m, 64);
        sxx += __shfl_xor(sxx, m, 64);
    }
    if (lane == 0) { stats_lds[wv][0] = sx; stats_lds[wv][1] = sxx; }
    __syncthreads();

    // Scalar phase, parallel over (row, plane): 128 threads, 16-lane reduce.
    if (t < RPB * Ph) {
        const int r = t >> 4, p = t & 15;
        float d1 = dots_lds[r][p]      + br[p];
        float d2 = dots_lds[r][Ph + p] + bo[p];
        float cd = cosf((tanhf(d1) - tanhf(d2)) * 3.14159265358979323846f);
#pragma unroll
        for (int m = 1; m < 16; m <<= 1) cd += __shfl_xor(cd, m, 16);
        if (p == 0) {
            float s    = cd;
            float gain = log1pf(expf(s * (1.f / Ph) + 0.5f));  // softplus
            float cm   = s * gain * (1.f / Ph);
            float mu   = stats_lds[r][0] * (1.f / Dh);
            float var  = stats_lds[r][1] * (1.f / Dh) - mu * mu;
            var = fmaxf(var, 0.f);
            float rstd  = rsqrtf(cm * cm * var + 1e-5f);
            float alpha = cm * rstd;
            scale_lds[r][0] = alpha;
            scale_lds[r][1] = alpha * mu;
        }
    }
    __syncthreads();

    // Phase B, column-sliced: wave wv owns cols [wv*512, wv*512+512);
    // gamma/beta loaded ONCE per wave, reused across all 8 rows. x re-read
    // is L2-hot; out stores non-temporal (never re-read; keeps L2 for x).
    {
        const int col0 = wv * 512 + lane * 4;
        const float4 g4a = *(const float4*)(gamma + col0);
        const float4 g4b = *(const float4*)(gamma + col0 + 256);
        const float4 b4a = *(const float4*)(beta  + col0);
        const float4 b4b = *(const float4*)(beta  + col0 + 256);
#pragma unroll
        for (int r = 0; r < RPB; ++r) {
            const float alpha = scale_lds[r][0];
            const float am    = scale_lds[r][1];
            const float* xr  = x   + (rowbase + r) * (size_t)Dh;
            float*       orw = out + (rowbase + r) * (size_t)Dh;
            float4 xa = *(const float4*)(xr + col0);
            float4 xb = *(const float4*)(xr + col0 + 256);
            float4n oa, ob;
            oa.x = xa.x + g4a.x * (alpha * xa.x - am) + b4a.x;
            oa.y = xa.y + g4a.y * (alpha * xa.y - am) + b4a.y;
            oa.z = xa.z + g4a.z * (alpha * xa.z - am) + b4a.z;
            oa.w = xa.w + g4a.w * (alpha * xa.w - am) + b4a.w;
            ob.x = xb.x + g4b.x * (alpha * xb.x - am) + b4b.x;
            ob.y = xb.y + g4b.y * (alpha * xb.y - am) + b4b.y;
            ob.z = xb.z + g4b.z * (alpha * xb.z - am) + b4b.z;
            ob.w = xb.w + g4b.w * (alpha * xb.w - am) + b4b.w;
            __builtin_nontemporal_store(oa, reinterpret_cast<float4n*>(orw + col0));
            __builtin_nontemporal_store(ob, reinterpret_cast<float4n*>(orw + col0 + 256));
        }
    }
}

extern "C" void kernel_launch(void* const* d_in, const int* in_sizes, int n_in,
                              void* d_out, int out_size, void* d_ws, size_t ws_size,
                              hipStream_t stream)
{
    const float* x     = (const float*)d_in[0];
    const float* Wr    = (const float*)d_in[1];
    const float* br    = (const float*)d_in[2];
    const float* Wo    = (const float*)d_in[3];
    const float* bo    = (const float*)d_in[4];
    const float* gamma = (const float*)d_in[5];
    const float* beta  = (const float*)d_in[6];
    float* out = (float*)d_out;

    const int B = in_sizes[0] / Dh;       // 32768
    dim3 grid(B / RPB);                   // 4096 blocks
    phase_fused<<<grid, BLOCK, 0, stream>>>(x, Wr, br, Wo, bo, gamma, beta, out);
}